// Round 1
// baseline (16.691 us; speedup 1.0000x reference)
//
#include <hip/hip_runtime.h>
#include <math.h>

#define HDIM 512
#define LDIM 256

// K1: gather loc_table rows, accumulate 4 weighted sums s[k][h] via atomics.
// grid 16 blocks x 256 threads; block b handles l in [b*16, b*16+16).
__global__ void k_gather(const float* __restrict__ td_u, const float* __restrict__ td_l,
                         const float* __restrict__ ld_u, const float* __restrict__ ld_l,
                         const float* __restrict__ table, const int* __restrict__ loc,
                         float* __restrict__ s /* 4*HDIM, pre-zeroed */) {
    __shared__ float w[16][4];
    const int b   = blockIdx.x;
    const int tid = threadIdx.x;
    if (tid < 16) {
        const int l = b * 16 + tid;
        const float a1 = td_u[l], b1 = td_l[l];
        const float beta = a1 / (a1 + b1);
        const float a2 = ld_u[l], b2 = ld_l[l];
        const float alpha = a2 / (a2 + b2);
        w[tid][0] = alpha * beta;
        w[tid][1] = alpha * (1.0f - beta);
        w[tid][2] = (1.0f - alpha) * beta;
        w[tid][3] = (1.0f - alpha) * (1.0f - beta);
    }
    __syncthreads();

    const int h2 = tid * 2;  // each thread owns 2 consecutive h (float2)
    float2 a0 = {0.f, 0.f}, a1v = {0.f, 0.f}, a2v = {0.f, 0.f}, a3v = {0.f, 0.f};
#pragma unroll 4
    for (int li = 0; li < 16; ++li) {
        const int l = b * 16 + li;
        const size_t row = (size_t)loc[l] * HDIM;
        const float2 e = *(const float2*)(table + row + h2);
        const float w0 = w[li][0], w1 = w[li][1], w2 = w[li][2], w3 = w[li][3];
        a0.x += w0 * e.x; a0.y += w0 * e.y;
        a1v.x += w1 * e.x; a1v.y += w1 * e.y;
        a2v.x += w2 * e.x; a2v.y += w2 * e.y;
        a3v.x += w3 * e.x; a3v.y += w3 * e.y;
    }
    atomicAdd(&s[0 * HDIM + h2],     a0.x);  atomicAdd(&s[0 * HDIM + h2 + 1], a0.y);
    atomicAdd(&s[1 * HDIM + h2],     a1v.x); atomicAdd(&s[1 * HDIM + h2 + 1], a1v.y);
    atomicAdd(&s[2 * HDIM + h2],     a2v.x); atomicAdd(&s[2 * HDIM + h2 + 1], a2v.y);
    atomicAdd(&s[3 * HDIM + h2],     a3v.x); atomicAdd(&s[3 * HDIM + h2 + 1], a3v.y);
}

// K2: t_up[i] = W_thU[i,:]·s1 + W_thL[i,:]·s2 ; t_lo[i] = W_thU[i,:]·s3 + W_thL[i,:]·s4
// grid 128 blocks x 256 threads; one wave (64 lanes) per output row.
__global__ void k_mid(const float* __restrict__ WU, const float* __restrict__ WL,
                      const float* __restrict__ s, float* __restrict__ t /* 2*HDIM */) {
    const int wave = threadIdx.x >> 6;
    const int lane = threadIdx.x & 63;
    const int i = blockIdx.x * 4 + wave;
    const float* wu = WU + (size_t)i * HDIM;
    const float* wl = WL + (size_t)i * HDIM;
    float pu = 0.f, pl = 0.f;
#pragma unroll
    for (int it = 0; it < 2; ++it) {
        const int j = it * 256 + lane * 4;
        const float4 u  = *(const float4*)(wu + j);
        const float4 l4 = *(const float4*)(wl + j);
        const float4 s1 = *(const float4*)(s + 0 * HDIM + j);
        const float4 s2 = *(const float4*)(s + 1 * HDIM + j);
        const float4 s3 = *(const float4*)(s + 2 * HDIM + j);
        const float4 s4 = *(const float4*)(s + 3 * HDIM + j);
        pu += u.x * s1.x + u.y * s1.y + u.z * s1.z + u.w * s1.w
            + l4.x * s2.x + l4.y * s2.y + l4.z * s2.z + l4.w * s2.w;
        pl += u.x * s3.x + u.y * s3.y + u.z * s3.z + u.w * s3.w
            + l4.x * s4.x + l4.y * s4.y + l4.z * s4.z + l4.w * s4.w;
    }
#pragma unroll
    for (int off = 32; off; off >>= 1) {
        pu += __shfl_down(pu, off);
        pl += __shfl_down(pl, off);
    }
    if (lane == 0) { t[i] = pu; t[HDIM + i] = pl; }
}

// K3: out[i] = sigmoid( W_shU[i,:]·t_up + W_shL[i,:]·t_lo + W_ih[i,:]·hx )
__global__ void k_out(const float* __restrict__ WshU, const float* __restrict__ WshL,
                      const float* __restrict__ Wih, const float* __restrict__ t,
                      const float* __restrict__ hx, float* __restrict__ out) {
    const int wave = threadIdx.x >> 6;
    const int lane = threadIdx.x & 63;
    const int i = blockIdx.x * 4 + wave;
    const float* wu = WshU + (size_t)i * HDIM;
    const float* wl = WshL + (size_t)i * HDIM;
    const float* wi = Wih + (size_t)i * HDIM;
    float p = 0.f;
#pragma unroll
    for (int it = 0; it < 2; ++it) {
        const int j = it * 256 + lane * 4;
        const float4 u  = *(const float4*)(wu + j);
        const float4 l4 = *(const float4*)(wl + j);
        const float4 wi4 = *(const float4*)(wi + j);
        const float4 tu = *(const float4*)(t + j);
        const float4 tl = *(const float4*)(t + HDIM + j);
        const float4 hv = *(const float4*)(hx + j);
        p += u.x * tu.x + u.y * tu.y + u.z * tu.z + u.w * tu.w
           + l4.x * tl.x + l4.y * tl.y + l4.z * tl.z + l4.w * tl.w
           + wi4.x * hv.x + wi4.y * hv.y + wi4.z * hv.z + wi4.w * hv.w;
    }
#pragma unroll
    for (int off = 32; off; off >>= 1) p += __shfl_down(p, off);
    if (lane == 0) out[i] = 1.0f / (1.0f + expf(-p));
}

extern "C" void kernel_launch(void* const* d_in, const int* in_sizes, int n_in,
                              void* d_out, int out_size, void* d_ws, size_t ws_size,
                              hipStream_t stream) {
    const float* td_u  = (const float*)d_in[0];
    const float* td_l  = (const float*)d_in[1];
    const float* ld_u  = (const float*)d_in[2];
    const float* ld_l  = (const float*)d_in[3];
    const float* hx    = (const float*)d_in[4];
    const float* W_ih  = (const float*)d_in[5];
    const float* W_thU = (const float*)d_in[6];
    const float* W_thL = (const float*)d_in[7];
    const float* W_shU = (const float*)d_in[8];
    const float* W_shL = (const float*)d_in[9];
    const float* table = (const float*)d_in[10];
    const int*   loc   = (const int*)d_in[11];

    float* s = (float*)d_ws;        // 4*HDIM partial-weighted sums
    float* t = s + 4 * HDIM;        // 2*HDIM: t_up, t_lo
    float* out = (float*)d_out;

    hipMemsetAsync(d_ws, 0, 4 * HDIM * sizeof(float), stream);
    k_gather<<<16, 256, 0, stream>>>(td_u, td_l, ld_u, ld_l, table, loc, s);
    k_mid<<<HDIM / 4, 256, 0, stream>>>(W_thU, W_thL, s, t);
    k_out<<<HDIM / 4, 256, 0, stream>>>(W_shU, W_shL, W_ih, t, hx, out);
}